// Round 2
// baseline (1340.869 us; speedup 1.0000x reference)
//
#include <hip/hip_runtime.h>

typedef _Float16 f16x8 __attribute__((ext_vector_type(8)));
typedef _Float16 f16x4 __attribute__((ext_vector_type(4)));
typedef float    f32x4 __attribute__((ext_vector_type(4)));

#define BM 128
#define BN 128
#define BK 32

// async global->LDS, 16B per lane. LDS dst must be wave-uniform base + lane*16.
__device__ __forceinline__ void gld16(const void* g, void* l) {
  __builtin_amdgcn_global_load_lds(
      (__attribute__((address_space(1))) void*)const_cast<void*>(g),
      (__attribute__((address_space(3))) void*)l, 16, 0, 0);
}

// Branchless: all 5 activations from two transcendentals, then lane-select.
// relu / sigmoid / tanh / leaky(0.1) / selu, followed by min(out, cap).
__device__ __forceinline__ float act_clip(int f, float v, float cap) {
  const float sc = 1.0507009873554805f, al = 1.6732632423543772f;
  const float av = fabsf(v);
  const float e  = expf(-av);        // exp(-|v|)  (== exp(v) when v<0)
  const float e2 = expf(-2.0f * av); // exp(-2|v|)
  const bool  pos = (v >= 0.0f);

  const float inv1 = 1.0f / (1.0f + e);
  const float sig  = pos ? inv1 : e * inv1;          // sigmoid(v)
  float th = (1.0f - e2) / (1.0f + e2);              // tanh(|v|)
  th = pos ? th : -th;
  const float rel = fmaxf(v, 0.0f);
  const float lk  = pos ? v : 0.1f * v;
  const float sel = pos ? sc * v : sc * al * (e - 1.0f);

  float out = rel;
  out = (f == 1) ? sig : out;
  out = (f == 2) ? th  : out;
  out = (f == 3) ? lk  : out;
  out = (f == 4) ? sel : out;
  return fminf(out, cap);
}

// C[M,N] = A[M,K] @ W[N,K]^T + bias, then per-column activation+clip.
// A and W given as f16 (hi,lo) split planes; fp32 accumulate via 3 MFMA products.
// Output: intermediate layers -> (Ohi,Olo) f16 split planes; final -> Ofin fp32.
// Grid: x = row-block (many, XCD round-robin keeps col-blocks of one row-group
// on one XCD), y = col-block.
__global__ __launch_bounds__(256) void gemm_split_act(
    const _Float16* __restrict__ Ahi, const _Float16* __restrict__ Alo,
    const _Float16* __restrict__ Whi, const _Float16* __restrict__ Wlo,
    const float* __restrict__ bias, const int* __restrict__ fid,
    const float* __restrict__ cap, int N, int K,
    _Float16* __restrict__ Ohi, _Float16* __restrict__ Olo,
    float* __restrict__ Ofin)
{
  __shared__ _Float16 sA[2][BM * BK];   // [hi/lo][row*BK + k], rows = batch
  __shared__ _Float16 sB[2][BN * BK];   // [hi/lo][row*BK + k], rows = out-feature

  const int tid  = threadIdx.x;
  const int lane = tid & 63;
  const int wave = tid >> 6;
  const int wm = (wave >> 1) * 64;      // wave's row offset in 128x128 tile
  const int wn = (wave & 1) * 64;       // wave's col offset
  const int ml = lane & 15;
  const int q  = lane >> 4;

  const long row0 = (long)blockIdx.x * BM;
  const int  col0 = blockIdx.y * BN;

  // staging: thread covers global rows (tid>>2) and 64+(tid>>2), 16B chunk (tid&3)
  const int srow = tid >> 2;
  const int scol = (tid & 3) * 8;       // f16 elements
  const _Float16* gAh = Ahi + (row0 + srow) * (long)K + scol;
  const _Float16* gAl = Alo + (row0 + srow) * (long)K + scol;
  const _Float16* gBh = Whi + (long)(col0 + srow) * K + scol;
  const _Float16* gBl = Wlo + (long)(col0 + srow) * K + scol;

  f32x4 acc[4][4] = {};

  for (int k0 = 0; k0 < K; k0 += BK) {
    gld16(gAh + k0,                &sA[0][tid * 8]);
    gld16(gAh + (long)64 * K + k0, &sA[0][64 * BK + tid * 8]);
    gld16(gAl + k0,                &sA[1][tid * 8]);
    gld16(gAl + (long)64 * K + k0, &sA[1][64 * BK + tid * 8]);
    gld16(gBh + k0,                &sB[0][tid * 8]);
    gld16(gBh + (long)64 * K + k0, &sB[0][64 * BK + tid * 8]);
    gld16(gBl + k0,                &sB[1][tid * 8]);
    gld16(gBl + (long)64 * K + k0, &sB[1][64 * BK + tid * 8]);
    __syncthreads();   // drains vmcnt: staging complete

    f16x8 ah[4], al[4], bh[4], bl[4];
#pragma unroll
    for (int i = 0; i < 4; i++) {
      ah[i] = *(const f16x8*)&sA[0][(wm + i * 16 + ml) * BK + q * 8];
      al[i] = *(const f16x8*)&sA[1][(wm + i * 16 + ml) * BK + q * 8];
    }
#pragma unroll
    for (int j = 0; j < 4; j++) {
      bh[j] = *(const f16x8*)&sB[0][(wn + j * 16 + ml) * BK + q * 8];
      bl[j] = *(const f16x8*)&sB[1][(wn + j * 16 + ml) * BK + q * 8];
    }
#pragma unroll
    for (int i = 0; i < 4; i++)
#pragma unroll
      for (int j = 0; j < 4; j++) {
        acc[i][j] = __builtin_amdgcn_mfma_f32_16x16x32_f16(ah[i], bh[j], acc[i][j], 0, 0, 0);
        acc[i][j] = __builtin_amdgcn_mfma_f32_16x16x32_f16(ah[i], bl[j], acc[i][j], 0, 0, 0);
        acc[i][j] = __builtin_amdgcn_mfma_f32_16x16x32_f16(al[i], bh[j], acc[i][j], 0, 0, 0);
      }
    __syncthreads();   // all frag reads done before next staging overwrites
  }

  // epilogue: C/D layout col = lane&15, row = (lane>>4)*4 + reg
#pragma unroll
  for (int j = 0; j < 4; j++) {
    const int col = col0 + wn + j * 16 + ml;
    const float bj = bias[col];
    const int   fj = fid[col];
    const float cj = cap[col];
#pragma unroll
    for (int i = 0; i < 4; i++) {
      const long rbase = row0 + wm + i * 16 + q * 4;
#pragma unroll
      for (int r = 0; r < 4; r++) {
        float v = act_clip(fj, acc[i][j][r] + bj, cj);
        const long idx = (rbase + r) * (long)N + col;
        if (Ofin) {
          Ofin[idx] = v;
        } else {
          _Float16 h = (_Float16)v;
          Ohi[idx] = h;
          Olo[idx] = (_Float16)(v - (float)h);
        }
      }
    }
  }
}

// fp32 -> (hi,lo) f16 split planes, 4 elems/thread
__global__ void split_f32(const float* __restrict__ x, _Float16* __restrict__ hi,
                          _Float16* __restrict__ lo, long n)
{
  long i = ((long)blockIdx.x * 256 + threadIdx.x) * 4;
  if (i >= n) return;
  float4 v = *(const float4*)(x + i);
  f16x4 h, l;
  h[0] = (_Float16)v.x; l[0] = (_Float16)(v.x - (float)h[0]);
  h[1] = (_Float16)v.y; l[1] = (_Float16)(v.y - (float)h[1]);
  h[2] = (_Float16)v.z; l[2] = (_Float16)(v.z - (float)h[2]);
  h[3] = (_Float16)v.w; l[3] = (_Float16)(v.w - (float)h[3]);
  *(f16x4*)(hi + i) = h;
  *(f16x4*)(lo + i) = l;
}

extern "C" void kernel_launch(void* const* d_in, const int* in_sizes, int n_in,
                              void* d_out, int out_size, void* d_ws, size_t ws_size,
                              hipStream_t stream)
{
  const float* input = (const float*)d_in[0];
  const float* W_in  = (const float*)d_in[1];
  const float* b_in  = (const float*)d_in[2];
  const float* W_h   = (const float*)d_in[3];
  const float* b_h   = (const float*)d_in[4];
  const float* W_out = (const float*)d_in[5];
  const float* b_out = (const float*)d_in[6];
  const float* m_in  = (const float*)d_in[7];
  const float* m_h   = (const float*)d_in[8];
  const float* m_out = (const float*)d_in[9];
  const int* fid_in  = (const int*)d_in[10];
  const int* fid_h   = (const int*)d_in[11];
  const int* fid_out = (const int*)d_in[12];

  const int X     = in_sizes[2];                 // 512
  const int D_IN  = in_sizes[1] / X;             // 512
  const int Z     = in_sizes[3] / (X * X);       // 4
  const int D_OUT = in_sizes[6];                 // 128
  const long B    = (long)in_sizes[0] / D_IN;    // 65536

  const long w_elems = (long)X * D_IN + (long)Z * X * X + (long)D_OUT * X;
  _Float16* Whi = (_Float16*)d_ws;
  _Float16* Wlo = Whi + w_elems;
  char* actbase = (char*)(Wlo + w_elems);

  // row chunking so 2 ping-pong activation buffers (hi+lo f16 each) fit in ws
  size_t wbytes = 4 * (size_t)w_elems;
  size_t avail  = ws_size > wbytes ? ws_size - wbytes : 0;
  long R = (long)(avail / (8 * (size_t)X));
  R = (R / BM) * BM;
  if (R > B) R = B;
  if (R < BM) R = BM;

  _Float16* bufhi[2];
  _Float16* buflo[2];
  bufhi[0] = (_Float16*)actbase;
  buflo[0] = bufhi[0] + R * (long)X;
  bufhi[1] = buflo[0] + R * (long)X;
  buflo[1] = bufhi[1] + R * (long)X;

  // split weights once per call
  {
    long n0 = (long)X * D_IN;
    long n1 = (long)Z * X * X;
    long n2 = (long)D_OUT * X;
    split_f32<<<(int)((n0 / 4 + 255) / 256), 256, 0, stream>>>(W_in, Whi, Wlo, n0);
    split_f32<<<(int)((n1 / 4 + 255) / 256), 256, 0, stream>>>(W_h, Whi + n0, Wlo + n0, n1);
    split_f32<<<(int)((n2 / 4 + 255) / 256), 256, 0, stream>>>(W_out, Whi + n0 + n1, Wlo + n0 + n1, n2);
  }

  const long woff_h   = (long)X * D_IN;
  const long woff_out = woff_h + (long)Z * X * X;

  for (long r0 = 0; r0 < B; r0 += R) {
    const long rows = (B - r0 < R) ? (B - r0) : R;

    // input chunk -> split planes
    {
      long n = rows * (long)D_IN;
      split_f32<<<(int)((n / 4 + 255) / 256), 256, 0, stream>>>(input + r0 * D_IN, bufhi[0], buflo[0], n);
    }

    // grid: x = row-blocks (many), y = col-blocks (few) -> col-blocks sharing an
    // A row-group get linear ids = x (mod gridX spacing) -> same XCD (512 % 8 == 0)
    dim3 gridH((unsigned)(rows / BM), X / BN);
    // layer 0: [rows, D_IN] x W_in[X, D_IN]^T
    gemm_split_act<<<gridH, 256, 0, stream>>>(bufhi[0], buflo[0], Whi, Wlo,
        b_in, fid_in, m_in, X, D_IN, bufhi[1], buflo[1], nullptr);
    int cur = 1;
    for (int i = 0; i < Z; i++) {
      const _Float16* wh = Whi + woff_h + (long)i * X * X;
      const _Float16* wl = Wlo + woff_h + (long)i * X * X;
      gemm_split_act<<<gridH, 256, 0, stream>>>(bufhi[cur], buflo[cur], wh, wl,
          b_h + (long)i * X, fid_h + (long)i * X, m_h + (long)i * X, X, X,
          bufhi[1 - cur], buflo[1 - cur], nullptr);
      cur ^= 1;
    }
    dim3 gridO((unsigned)(rows / BM), D_OUT / BN);
    gemm_split_act<<<gridO, 256, 0, stream>>>(bufhi[cur], buflo[cur],
        Whi + woff_out, Wlo + woff_out, b_out, fid_out, m_out, D_OUT, X,
        nullptr, nullptr, (float*)d_out + r0 * (long)D_OUT);
  }
}

// Round 3
// 989.459 us; speedup vs baseline: 1.3552x; 1.3552x over previous
//
#include <hip/hip_runtime.h>

typedef _Float16 f16x8 __attribute__((ext_vector_type(8)));
typedef _Float16 f16x4 __attribute__((ext_vector_type(4)));
typedef float    f32x4 __attribute__((ext_vector_type(4)));

#define BM 128
#define BN 128
#define BK 32

// async global->LDS, 16B per lane. LDS dst must be wave-uniform base + lane*16.
__device__ __forceinline__ void gld16(const void* g, void* l) {
  __builtin_amdgcn_global_load_lds(
      (__attribute__((address_space(1))) void*)const_cast<void*>(g),
      (__attribute__((address_space(3))) void*)l, 16, 0, 0);
}

// Branchless activations from ONE native exp:
//   e = exp(-|v|), e2 = e*e = exp(-2|v|); fast v_rcp for the divides.
// relu / sigmoid / tanh / leaky(0.1) / selu, then min(out, cap).
__device__ __forceinline__ float act_clip(int f, float v, float cap) {
  const float sc = 1.0507009873554805f, al = 1.6732632423543772f;
  const float av = fabsf(v);
  const float e  = __expf(-av);
  const float e2 = e * e;
  const bool  pos = (v >= 0.0f);

  const float r1 = __builtin_amdgcn_rcpf(1.0f + e);
  const float sig = pos ? r1 : e * r1;                 // sigmoid(v)
  float th = (1.0f - e2) * __builtin_amdgcn_rcpf(1.0f + e2);
  th = pos ? th : -th;                                  // tanh(v)
  const float rel = fmaxf(v, 0.0f);
  const float lk  = pos ? v : 0.1f * v;
  const float sel = pos ? sc * v : sc * al * (e - 1.0f);

  float out = rel;
  out = (f == 1) ? sig : out;
  out = (f == 2) ? th  : out;
  out = (f == 3) ? lk  : out;
  out = (f == 4) ? sel : out;
  return fminf(out, cap);
}

// C[M,N] = A[M,K] @ W[N,K]^T + bias, then per-column activation+clip.
// A and W as f16 (hi,lo) split planes; fp32 accumulate via 3 MFMA products.
// Output: intermediate layers -> (Ohi,Olo) split planes; final -> Ofin fp32.
// 1D grid with XCD swizzle: id = xcd + 8*(c + nCol*g), r = 8g+xcd ->
// each XCD runs all col-blocks of one row-group back-to-back (A-tile stays
// in its L2) and W tiles (1 MB/layer) stay L2-resident across row-groups.
__global__ __launch_bounds__(256, 4) void gemm_split_act(
    const _Float16* __restrict__ Ahi, const _Float16* __restrict__ Alo,
    const _Float16* __restrict__ Whi, const _Float16* __restrict__ Wlo,
    const float* __restrict__ bias, const int* __restrict__ fid,
    const float* __restrict__ cap, int N, int K, int nCol, int nRow,
    _Float16* __restrict__ Ohi, _Float16* __restrict__ Olo,
    float* __restrict__ Ofin)
{
  __shared__ _Float16 sA[2][BM * BK];   // [hi/lo][row*BK + k], rows = batch
  __shared__ _Float16 sB[2][BN * BK];   // [hi/lo][row*BK + k], rows = out-feature

  const int tid  = threadIdx.x;
  const int lane = tid & 63;
  const int wave = tid >> 6;
  const int wm = (wave >> 1) * 64;      // wave's row offset in 128x128 tile
  const int wn = (wave & 1) * 64;       // wave's col offset
  const int ml = lane & 15;
  const int q  = lane >> 4;

  int rb, cb;
  if ((nRow & 7) == 0) {
    const int id = blockIdx.x;
    const int xcd = id & 7, slot = id >> 3;
    cb = slot % nCol;
    rb = (slot / nCol) * 8 + xcd;
  } else {
    cb = blockIdx.x % nCol;
    rb = blockIdx.x / nCol;
  }

  const long row0 = (long)rb * BM;
  const int  col0 = cb * BN;

  // staging: thread covers global rows (tid>>2) and 64+(tid>>2), 16B chunk (tid&3)
  const int srow = tid >> 2;
  const int scol = (tid & 3) * 8;       // f16 elements
  const _Float16* gAh = Ahi + (row0 + srow) * (long)K + scol;
  const _Float16* gAl = Alo + (row0 + srow) * (long)K + scol;
  const _Float16* gBh = Whi + (long)(col0 + srow) * K + scol;
  const _Float16* gBl = Wlo + (long)(col0 + srow) * K + scol;

  f32x4 acc[4][4] = {};

  for (int k0 = 0; k0 < K; k0 += BK) {
    gld16(gAh + k0,                &sA[0][tid * 8]);
    gld16(gAh + (long)64 * K + k0, &sA[0][64 * BK + tid * 8]);
    gld16(gAl + k0,                &sA[1][tid * 8]);
    gld16(gAl + (long)64 * K + k0, &sA[1][64 * BK + tid * 8]);
    gld16(gBh + k0,                &sB[0][tid * 8]);
    gld16(gBh + (long)64 * K + k0, &sB[0][64 * BK + tid * 8]);
    gld16(gBl + k0,                &sB[1][tid * 8]);
    gld16(gBl + (long)64 * K + k0, &sB[1][64 * BK + tid * 8]);
    __syncthreads();   // drains vmcnt: staging complete

    f16x8 ah[4], al[4], bh[4], bl[4];
#pragma unroll
    for (int i = 0; i < 4; i++) {
      ah[i] = *(const f16x8*)&sA[0][(wm + i * 16 + ml) * BK + q * 8];
      al[i] = *(const f16x8*)&sA[1][(wm + i * 16 + ml) * BK + q * 8];
    }
#pragma unroll
    for (int j = 0; j < 4; j++) {
      bh[j] = *(const f16x8*)&sB[0][(wn + j * 16 + ml) * BK + q * 8];
      bl[j] = *(const f16x8*)&sB[1][(wn + j * 16 + ml) * BK + q * 8];
    }
#pragma unroll
    for (int i = 0; i < 4; i++)
#pragma unroll
      for (int j = 0; j < 4; j++) {
        acc[i][j] = __builtin_amdgcn_mfma_f32_16x16x32_f16(ah[i], bh[j], acc[i][j], 0, 0, 0);
        acc[i][j] = __builtin_amdgcn_mfma_f32_16x16x32_f16(ah[i], bl[j], acc[i][j], 0, 0, 0);
        acc[i][j] = __builtin_amdgcn_mfma_f32_16x16x32_f16(al[i], bh[j], acc[i][j], 0, 0, 0);
      }
    __syncthreads();   // all frag reads done before next staging overwrites
  }

  // epilogue: C/D layout col = lane&15, row = (lane>>4)*4 + reg
#pragma unroll
  for (int j = 0; j < 4; j++) {
    const int col = col0 + wn + j * 16 + ml;
    const float bj = bias[col];
    const int   fj = fid[col];
    const float cj = cap[col];
#pragma unroll
    for (int i = 0; i < 4; i++) {
      const long rbase = row0 + wm + i * 16 + q * 4;
#pragma unroll
      for (int r = 0; r < 4; r++) {
        float v = act_clip(fj, acc[i][j][r] + bj, cj);
        const long idx = (rbase + r) * (long)N + col;
        if (Ofin) {
          Ofin[idx] = v;
        } else {
          _Float16 h = (_Float16)v;
          Ohi[idx] = h;
          Olo[idx] = (_Float16)(v - (float)h);
        }
      }
    }
  }
}

// fp32 -> (hi,lo) f16 split planes, 4 elems/thread
__global__ void split_f32(const float* __restrict__ x, _Float16* __restrict__ hi,
                          _Float16* __restrict__ lo, long n)
{
  long i = ((long)blockIdx.x * 256 + threadIdx.x) * 4;
  if (i >= n) return;
  float4 v = *(const float4*)(x + i);
  f16x4 h, l;
  h[0] = (_Float16)v.x; l[0] = (_Float16)(v.x - (float)h[0]);
  h[1] = (_Float16)v.y; l[1] = (_Float16)(v.y - (float)h[1]);
  h[2] = (_Float16)v.z; l[2] = (_Float16)(v.z - (float)h[2]);
  h[3] = (_Float16)v.w; l[3] = (_Float16)(v.w - (float)h[3]);
  *(f16x4*)(hi + i) = h;
  *(f16x4*)(lo + i) = l;
}

extern "C" void kernel_launch(void* const* d_in, const int* in_sizes, int n_in,
                              void* d_out, int out_size, void* d_ws, size_t ws_size,
                              hipStream_t stream)
{
  const float* input = (const float*)d_in[0];
  const float* W_in  = (const float*)d_in[1];
  const float* b_in  = (const float*)d_in[2];
  const float* W_h   = (const float*)d_in[3];
  const float* b_h   = (const float*)d_in[4];
  const float* W_out = (const float*)d_in[5];
  const float* b_out = (const float*)d_in[6];
  const float* m_in  = (const float*)d_in[7];
  const float* m_h   = (const float*)d_in[8];
  const float* m_out = (const float*)d_in[9];
  const int* fid_in  = (const int*)d_in[10];
  const int* fid_h   = (const int*)d_in[11];
  const int* fid_out = (const int*)d_in[12];

  const int X     = in_sizes[2];                 // 512
  const int D_IN  = in_sizes[1] / X;             // 512
  const int Z     = in_sizes[3] / (X * X);       // 4
  const int D_OUT = in_sizes[6];                 // 128
  const long B    = (long)in_sizes[0] / D_IN;    // 65536

  const long w_elems = (long)X * D_IN + (long)Z * X * X + (long)D_OUT * X;
  _Float16* Whi = (_Float16*)d_ws;
  _Float16* Wlo = Whi + w_elems;
  char* actbase = (char*)(Wlo + w_elems);

  // row chunking so 2 ping-pong activation buffers (hi+lo f16 each) fit in ws
  size_t wbytes = 4 * (size_t)w_elems;
  size_t avail  = ws_size > wbytes ? ws_size - wbytes : 0;
  long R = (long)(avail / (8 * (size_t)X));
  R = (R / BM) * BM;
  if (R > B) R = B;
  if (R < BM) R = BM;

  _Float16* bufhi[2];
  _Float16* buflo[2];
  bufhi[0] = (_Float16*)actbase;
  buflo[0] = bufhi[0] + R * (long)X;
  bufhi[1] = buflo[0] + R * (long)X;
  buflo[1] = bufhi[1] + R * (long)X;

  // split weights once per call
  {
    long n0 = (long)X * D_IN;
    long n1 = (long)Z * X * X;
    long n2 = (long)D_OUT * X;
    split_f32<<<(int)((n0 / 4 + 255) / 256), 256, 0, stream>>>(W_in, Whi, Wlo, n0);
    split_f32<<<(int)((n1 / 4 + 255) / 256), 256, 0, stream>>>(W_h, Whi + n0, Wlo + n0, n1);
    split_f32<<<(int)((n2 / 4 + 255) / 256), 256, 0, stream>>>(W_out, Whi + n0 + n1, Wlo + n0 + n1, n2);
  }

  const long woff_h   = (long)X * D_IN;
  const long woff_out = woff_h + (long)Z * X * X;

  for (long r0 = 0; r0 < B; r0 += R) {
    const long rows = (B - r0 < R) ? (B - r0) : R;

    // input chunk -> split planes
    {
      long n = rows * (long)D_IN;
      split_f32<<<(int)((n / 4 + 255) / 256), 256, 0, stream>>>(input + r0 * D_IN, bufhi[0], buflo[0], n);
    }

    const int nRow  = (int)(rows / BM);
    const int nColH = X / BN;
    dim3 gridH((unsigned)(nRow * nColH));
    // layer 0: [rows, D_IN] x W_in[X, D_IN]^T
    gemm_split_act<<<gridH, 256, 0, stream>>>(bufhi[0], buflo[0], Whi, Wlo,
        b_in, fid_in, m_in, X, D_IN, nColH, nRow, bufhi[1], buflo[1], nullptr);
    int cur = 1;
    for (int i = 0; i < Z; i++) {
      const _Float16* wh = Whi + woff_h + (long)i * X * X;
      const _Float16* wl = Wlo + woff_h + (long)i * X * X;
      gemm_split_act<<<gridH, 256, 0, stream>>>(bufhi[cur], buflo[cur], wh, wl,
          b_h + (long)i * X, fid_h + (long)i * X, m_h + (long)i * X, X, X,
          nColH, nRow, bufhi[1 - cur], buflo[1 - cur], nullptr);
      cur ^= 1;
    }
    const int nColO = D_OUT / BN;
    dim3 gridO((unsigned)(nRow * nColO));
    gemm_split_act<<<gridO, 256, 0, stream>>>(bufhi[cur], buflo[cur],
        Whi + woff_out, Wlo + woff_out, b_out, fid_out, m_out, D_OUT, X,
        nColO, nRow, nullptr, nullptr, (float*)d_out + r0 * (long)D_OUT);
  }
}